// Round 8
// baseline (249.143 us; speedup 1.0000x reference)
//
#include <hip/hip_runtime.h>
#include <hip/hip_bf16.h>
#include <cmath>

#define N_NODES 8192
#define F_INPUT 59
#define H 128
#define K 32
#define NECK 512
#define GPER 8
#define NG 1024
#define EPS_BN 1e-5f
#define DPITCH 136   // bf16 row pitch for neck staging (272 B)
#define XPITCH 72    // proj x-plane pitch (144 B)
#define PLANE 272    // padded plane stride (shorts) for edge A-frag planes (544 B)

typedef short bf16x8 __attribute__((ext_vector_type(8)));
typedef float f32x16 __attribute__((ext_vector_type(16)));

// truncation hi/lo split
__device__ __forceinline__ void split_bf(float v, short& hi, short& lo) {
    unsigned u = __float_as_uint(v);
    float hif = __uint_as_float(u & 0xffff0000u);
    hi = (short)(u >> 16);
    lo = (short)(__float_as_uint(v - hif) >> 16);
}
// round-to-nearest bf16
__device__ __forceinline__ short f2bfrn(float f) {
    __hip_bfloat16 b = __float2bfloat16(f);
    return *reinterpret_cast<short*>(&b);
}

// B-frag flat index for 32x32x16: c = ct*32+ln, k = s*16+hf*8+kk
__device__ __forceinline__ int bfrag_idx(int k, int c, int k16) {
    int ct = c >> 5, ln = c & 31;
    int s = k >> 4, hf = (k >> 3) & 1, kk = k & 7;
    return ((((ct * k16 + s) * 2 + hf) * 32 + ln) * 8 + kk);
}

// ---------------------------------------------------------------------------
// Prep (fused):
//   [0,59)   : row f of W3 = [lin_w | src_w@attnn_w | dst_w@attnn_w] -> pack
//   59       : zero-pad W3 rows k=59..63
//   60       : pack posnn_w -> B-frag (K16=1, K padded 6->16)
//   [61,125) : pack attnn_w, columns pre-scaled by attnn BN scale (K16=8)
//   [125,381): pack neck_w (K16=8)
// ---------------------------------------------------------------------------
__global__ __launch_bounds__(256) void prep_kernel(
    const float* __restrict__ lin_w,
    const float* __restrict__ src_w, const float* __restrict__ dst_w,
    const float* __restrict__ posnn_w,
    const float* __restrict__ attnn_w, const float* __restrict__ attnn_g,
    const float* __restrict__ neck_w,
    short* __restrict__ w3hi, short* __restrict__ w3lo,
    short* __restrict__ pwhi, short* __restrict__ pwlo,
    short* __restrict__ awhi, short* __restrict__ awlo,
    short* __restrict__ nwhi, short* __restrict__ nwlo)
{
    const int b = blockIdx.x;
    if (b < F_INPUT) {
        const int c = threadIdx.x;
        if (c < H) {
            float a1 = 0.f, a2 = 0.f;
            for (int k = 0; k < H; k++) {
                float wa = attnn_w[k * H + c];
                a1 = fmaf(src_w[b * H + k], wa, a1);
                a2 = fmaf(dst_w[b * H + k], wa, a2);
            }
            short hi, lo; int idx;
            split_bf(lin_w[b * H + c], hi, lo);
            idx = bfrag_idx(b, c, 4);       w3hi[idx] = hi; w3lo[idx] = lo;
            split_bf(a1, hi, lo);
            idx = bfrag_idx(b, 128 + c, 4); w3hi[idx] = hi; w3lo[idx] = lo;
            split_bf(a2, hi, lo);
            idx = bfrag_idx(b, 256 + c, 4); w3hi[idx] = hi; w3lo[idx] = lo;
        }
    } else if (b == F_INPUT) {
        for (int t = threadIdx.x; t < 5 * 384; t += 256) {
            int k = F_INPUT + t / 384, c = t % 384;
            int idx = bfrag_idx(k, c, 4);
            w3hi[idx] = 0; w3lo[idx] = 0;
        }
    } else if (b == F_INPUT + 1) {
        // posnn pack: 2048 entries, K16=1
        for (int idx = threadIdx.x; idx < 2048; idx += 256) {
            int kk = idx & 7; int t = idx >> 3;
            int l2 = t & 31; t >>= 5;
            int hb = t & 1;  t >>= 1;
            int ct = t;
            int k = hb * 8 + kk, c = ct * 32 + l2;
            float wv = (k < 6) ? posnn_w[k * H + c] : 0.f;
            short hi, lo; split_bf(wv, hi, lo);
            pwhi[idx] = hi; pwlo[idx] = lo;
        }
    } else if (b < F_INPUT + 2 + 64) {
        int idx = (b - F_INPUT - 2) * 256 + threadIdx.x;
        int kk = idx & 7; int t = idx >> 3;
        int l2 = t & 31; t >>= 5;
        int hb = t & 1;  t >>= 1;
        int s  = t & 7;  t >>= 3;
        int c = t * 32 + l2, k = s * 16 + hb * 8 + kk;
        float scale = attnn_g[c] * rsqrtf(1.f + EPS_BN);
        short hi, lo; split_bf(attnn_w[k * H + c] * scale, hi, lo);
        awhi[idx] = hi; awlo[idx] = lo;
    } else {
        int idx = (b - F_INPUT - 2 - 64) * 256 + threadIdx.x;
        int kk = idx & 7; int t = idx >> 3;
        int l2 = t & 31; t >>= 5;
        int hb = t & 1;  t >>= 1;
        int s  = t & 7;  t >>= 3;
        int c = t * 32 + l2, k = s * 16 + hb * 8 + kk;
        short hi, lo; split_bf(neck_w[k * NECK + c], hi, lo);
        nwhi[idx] = hi; nwlo[idx] = lo;
    }
}

// ---------------------------------------------------------------------------
// Kernel A: proj via MFMA. Block = 32 nodes, 4 waves. attnn BN scale folded:
//   vx[node][c] = (as_*xs, v);  xdb[node][c] = as_*xd + (as_*attnn_b + attnn_bb)
// ---------------------------------------------------------------------------
__global__ __launch_bounds__(256) void proj_kernel(
    const float* __restrict__ x, const float* __restrict__ lin_b,
    const float* __restrict__ attnn_g, const float* __restrict__ attnn_b,
    const float* __restrict__ attnn_bb,
    const short* __restrict__ w3hi, const short* __restrict__ w3lo,
    float2* __restrict__ vx, float* __restrict__ xdb)
{
    const int n0 = blockIdx.x * 32;
    const int tid = threadIdx.x;
    const int wave = tid >> 6;
    const int lane = tid & 63;
    const int hf = lane >> 5;
    const int ln = lane & 31;

    __shared__ __align__(16) short xhi[32][XPITCH];
    __shared__ __align__(16) short xlo[32][XPITCH];

    for (int idx = tid; idx < 32 * F_INPUT; idx += 256) {
        int n = idx / F_INPUT, k = idx - n * F_INPUT;
        short hi, lo; split_bf(x[n0 * F_INPUT + idx], hi, lo);
        xhi[n][k] = hi; xlo[n][k] = lo;
    }
    if (tid < 32 * 5) {
        int n = tid / 5, k = F_INPUT + tid % 5;
        xhi[n][k] = 0; xlo[n][k] = 0;
    }
    __syncthreads();

    f32x16 acc[3];
    #pragma unroll
    for (int t = 0; t < 3; t++)
        #pragma unroll
        for (int r = 0; r < 16; r++) acc[t][r] = 0.f;

    #pragma unroll
    for (int s = 0; s < 4; s++) {
        bf16x8 ah = *(const bf16x8*)&xhi[ln][s * 16 + hf * 8];
        bf16x8 al = *(const bf16x8*)&xlo[ln][s * 16 + hf * 8];
        #pragma unroll
        for (int t = 0; t < 3; t++) {
            const int ct = wave + 4 * t;
            const int boff = (((ct * 4 + s) * 2 + hf) * 32 + ln) * 8;
            bf16x8 bh = *(const bf16x8*)&w3hi[boff];
            bf16x8 bl = *(const bf16x8*)&w3lo[boff];
            acc[t] = __builtin_amdgcn_mfma_f32_32x32x16_bf16(ah, bl, acc[t], 0, 0, 0);
            acc[t] = __builtin_amdgcn_mfma_f32_32x32x16_bf16(al, bh, acc[t], 0, 0, 0);
            acc[t] = __builtin_amdgcn_mfma_f32_32x32x16_bf16(ah, bh, acc[t], 0, 0, 0);
        }
    }
    const int c = wave * 32 + ln;
    const float lb  = lin_b[c];
    const float as_ = attnn_g[c] * rsqrtf(1.f + EPS_BN);
    const float cbn = fmaf(attnn_b[c], as_, attnn_bb[c]);
    #pragma unroll
    for (int r = 0; r < 16; r++) {
        int node = n0 + (r & 3) + 8 * (r >> 2) + 4 * hf;
        vx[node * H + c] = make_float2(as_ * acc[1][r], acc[0][r] + lb);
        xdb[node * H + c] = fmaf(acc[2][r], as_, cbn);
    }
}

// ---------------------------------------------------------------------------
// Kernel B: edge, 2 nodes/block (grid 4096). Lane-contiguous A-frag planes:
//   rel planes [n][hf] of 32x8 shorts (PLANE stride), delta planes [n][s][hf].
// Delta kept in fp32 regs for the epilogue; LDS delta is single bf16 (RN).
// attnn weights pre-scaled by BN scale; epilogue alpha = relu(acc+base-g.x).
// ---------------------------------------------------------------------------
__global__ __launch_bounds__(256) void edge_kernel(
    const float* __restrict__ pos, const float* __restrict__ normal,
    const int* __restrict__ src,
    const float2* __restrict__ vx, const float* __restrict__ xdb,
    const float* __restrict__ posnn_b, const float* __restrict__ posnn_g,
    const float* __restrict__ posnn_bb,
    const short* __restrict__ pwhi, const short* __restrict__ pwlo,
    const short* __restrict__ awhi, const short* __restrict__ awlo,
    unsigned* __restrict__ h2)
{
    const int i0 = blockIdx.x * 2;
    const int tid = threadIdx.x;
    const int wave = tid >> 6;
    const int lane = tid & 63;
    const int hf = lane >> 5;
    const int ln = lane & 31;

    __shared__ int srcs[2][K];
    __shared__ __align__(16) short relh[4 * PLANE];   // planes [n*2+hf]
    __shared__ __align__(16) short rell[4 * PLANE];
    __shared__ __align__(16) short dpk[32 * PLANE];   // planes [(n*8+s)*2+hf]

    if (tid < 64) {
        int n = tid >> 5, jj = tid & 31;
        int i = i0 + n;
        int s = src[i * K + jj];
        srcs[n][jj] = s;
        short h_, l_;
        const int b0 = (n * 2) * PLANE + jj * 8;       // hf=0 plane
        const int b1 = (n * 2 + 1) * PLANE + jj * 8;   // hf=1 plane
        #pragma unroll
        for (int k = 0; k < 3; k++) {
            split_bf(pos[i * 3 + k] - pos[s * 3 + k], h_, l_);
            relh[b0 + k] = h_; rell[b0 + k] = l_;
            split_bf(normal[i * 3 + k] - normal[s * 3 + k], h_, l_);
            relh[b0 + k + 3] = h_; rell[b0 + k + 3] = l_;
        }
        #pragma unroll
        for (int k = 6; k < 8; k++) { relh[b0 + k] = 0; rell[b0 + k] = 0; }
        #pragma unroll
        for (int k = 0; k < 8; k++) { relh[b1 + k] = 0; rell[b1 + k] = 0; }
    }

    const int cc = wave * 32 + ln;
    const float ps  = posnn_g[cc] * rsqrtf(1.f + EPS_BN);
    const float pbn = fmaf(posnn_b[cc], ps, posnn_bb[cc]);

    // posnn B-frag (K16=1, ct=wave)
    const bf16x8 pbh = *(const bf16x8*)&pwhi[((wave * 2 + hf) * 32 + ln) * 8];
    const bf16x8 pbl = *(const bf16x8*)&pwlo[((wave * 2 + hf) * 32 + ln) * 8];

    // delta write position for this lane (row j varies per r)
    const int dbase = ((cc >> 4) * 2 + ((cc >> 3) & 1)) * PLANE + (cc & 7);

    __syncthreads();

    // ---- delta via MFMA, kept in regs + bf16(RN) to LDS planes
    float dreg[2][16];
    #pragma unroll
    for (int n = 0; n < 2; n++) {
        bf16x8 ah = *(const bf16x8*)&relh[(n * 2 + hf) * PLANE + ln * 8];
        bf16x8 al = *(const bf16x8*)&rell[(n * 2 + hf) * PLANE + ln * 8];
        f32x16 da;
        #pragma unroll
        for (int r = 0; r < 16; r++) da[r] = 0.f;
        da = __builtin_amdgcn_mfma_f32_32x32x16_bf16(ah, pbl, da, 0, 0, 0);
        da = __builtin_amdgcn_mfma_f32_32x32x16_bf16(al, pbh, da, 0, 0, 0);
        da = __builtin_amdgcn_mfma_f32_32x32x16_bf16(ah, pbh, da, 0, 0, 0);
        #pragma unroll
        for (int r = 0; r < 16; r++) {
            int j = (r & 3) + 8 * (r >> 2) + 4 * hf;
            float d = fmaxf(fmaf(da[r], ps, pbn), 0.f);
            dreg[n][r] = d;
            dpk[n * 16 * PLANE + dbase + j * 8] = f2bfrn(d);
        }
    }
    __syncthreads();

    // ---- attnn MFMA (weights pre-scaled) + softmax epilogue per node
    const short* whb = awhi + wave * 8 * 2 * 32 * 8;
    const short* wlb = awlo + wave * 8 * 2 * 32 * 8;

    #pragma clang loop unroll(disable)
    for (int n = 0; n < 2; n++) {
        const int i = i0 + n;
        f32x16 acc;
        #pragma unroll
        for (int r = 0; r < 16; r++) acc[r] = 0.f;
        #pragma unroll
        for (int s = 0; s < 8; s++) {
            bf16x8 ah = *(const bf16x8*)&dpk[((n * 8 + s) * 2 + hf) * PLANE + ln * 8];
            const int boff = ((s * 2 + hf) * 32 + ln) * 8;
            bf16x8 bh = *(const bf16x8*)&whb[boff];
            bf16x8 bl = *(const bf16x8*)&wlb[boff];
            acc = __builtin_amdgcn_mfma_f32_32x32x16_bf16(ah, bh, acc, 0, 0, 0);
            acc = __builtin_amdgcn_mfma_f32_32x32x16_bf16(ah, bl, acc, 0, 0, 0);
        }

        const float base = xdb[i * H + cc];
        float a[16], vv[16];
        float m = 0.f;   // relu floor
        #pragma unroll
        for (int r = 0; r < 16; r++) {
            int j = (r & 3) + 8 * (r >> 2) + 4 * hf;
            float2 g = vx[srcs[n][j] * H + cc];
            float av = fmaxf(acc[r] + base - g.x, 0.f);
            a[r] = av; vv[r] = g.y;
            m = fmaxf(m, av);
        }
        m = fmaxf(m, __shfl_xor(m, 32, 64));
        float den = 0.f;
        #pragma unroll
        for (int r = 0; r < 16; r++) {
            float e = __expf(a[r] - m);
            a[r] = e; den += e;
        }
        den += __shfl_xor(den, 32, 64);
        const float inv = 1.f / (den + 1e-16f);

        float hsum = 0.f;
        #pragma unroll
        for (int r = 0; r < 16; r++)
            hsum = fmaf(a[r], vv[r] + dreg[n][r], hsum);
        hsum += __shfl_xor(hsum, 32, 64);
        hsum *= inv;
        if (hf == 0) {
            unsigned u = __float_as_uint(hsum);
            unsigned hib = u & 0xffff0000u;
            unsigned lo = __float_as_uint(hsum - __uint_as_float(hib)) >> 16;
            h2[i * H + cc] = (lo << 16) | (u >> 16);
        }
    }
}

// ---------------------------------------------------------------------------
// Kernel C (fused): neck MFMA + bn_relu + residue max-pool + head.
// ---------------------------------------------------------------------------
__global__ __launch_bounds__(256) void neck_head_kernel(
    const unsigned* __restrict__ h2,
    const short* __restrict__ nwhi, const short* __restrict__ nwlo,
    const float* __restrict__ neck_b, const float* __restrict__ neck_g,
    const float* __restrict__ neck_bb,
    const float* __restrict__ mask_t,
    const float* __restrict__ mlp1_w, const float* __restrict__ mlp1_b,
    const float* __restrict__ mlp1_g, const float* __restrict__ mlp1_bb,
    const float* __restrict__ mlp2_w, const float* __restrict__ mlp2_b,
    float* __restrict__ out)
{
    const int blk = blockIdx.x;
    const int n0 = blk * 32;
    const int tid = threadIdx.x;
    const int wave = tid >> 6;
    const int lane = tid & 63;
    const int hf = lane >> 5;
    const int ln = lane & 31;

    __shared__ __align__(16) short a_hi[32][DPITCH];
    __shared__ __align__(16) short a_lo[32][DPITCH];
    __shared__ float gfeat_l[4][NECK];
    __shared__ float red_l[4][4][256];

    for (int d = tid; d < 32 * H; d += 256) {
        unsigned u = h2[(n0 + (d >> 7)) * H + (d & 127)];
        a_hi[d >> 7][d & 127] = (short)(u & 0xffffu);
        a_lo[d >> 7][d & 127] = (short)(u >> 16);
    }
    __syncthreads();

    f32x16 acc[4];
    #pragma unroll
    for (int t = 0; t < 4; t++)
        #pragma unroll
        for (int r = 0; r < 16; r++) acc[t][r] = 0.f;

    #pragma unroll
    for (int s = 0; s < 8; s++) {
        bf16x8 ah = *(const bf16x8*)&a_hi[ln][s * 16 + hf * 8];
        bf16x8 al = *(const bf16x8*)&a_lo[ln][s * 16 + hf * 8];
        #pragma unroll
        for (int t = 0; t < 4; t++) {
            const int ct = wave * 4 + t;
            const int boff = (((ct * 8 + s) * 2 + hf) * 32 + ln) * 8;
            bf16x8 bh = *(const bf16x8*)&nwhi[boff];
            bf16x8 bl = *(const bf16x8*)&nwlo[boff];
            acc[t] = __builtin_amdgcn_mfma_f32_32x32x16_bf16(ah, bl, acc[t], 0, 0, 0);
            acc[t] = __builtin_amdgcn_mfma_f32_32x32x16_bf16(al, bh, acc[t], 0, 0, 0);
            acc[t] = __builtin_amdgcn_mfma_f32_32x32x16_bf16(ah, bh, acc[t], 0, 0, 0);
        }
    }

    #pragma unroll
    for (int t = 0; t < 4; t++) {
        const int c = wave * 128 + t * 32 + ln;
        const float s  = neck_g[c] * rsqrtf(1.f + EPS_BN);
        const float bnb = fmaf(neck_b[c], s, neck_bb[c]);
        #pragma unroll
        for (int g = 0; g < 4; g++) {
            float m = 0.f;
            #pragma unroll
            for (int q = 0; q < 4; q++)
                m = fmaxf(m, fmaf(acc[t][4 * g + q], s, bnb));
            m = fmaxf(m, __shfl_xor(m, 32, 64));
            if (hf == 0) gfeat_l[g][c] = m;
        }
    }
    __syncthreads();

    const int c4 = lane;
    float ph[4][4];
    #pragma unroll
    for (int g = 0; g < 4; g++)
        #pragma unroll
        for (int mm = 0; mm < 4; mm++) ph[g][mm] = 0.f;

    const int k0 = wave * 128;
    for (int k = 0; k < 128; k += 4) {
        float4 gv[4];
        #pragma unroll
        for (int g = 0; g < 4; g++) gv[g] = *(const float4*)&gfeat_l[g][k0 + k];
        #pragma unroll
        for (int kk = 0; kk < 4; kk++) {
            float w0 = mlp1_w[(k0 + k + kk) * 256 + c4];
            float w1 = mlp1_w[(k0 + k + kk) * 256 + c4 + 64];
            float w2 = mlp1_w[(k0 + k + kk) * 256 + c4 + 128];
            float w3 = mlp1_w[(k0 + k + kk) * 256 + c4 + 192];
            #pragma unroll
            for (int g = 0; g < 4; g++) {
                float gvk = (&gv[g].x)[kk];
                ph[g][0] = fmaf(gvk, w0, ph[g][0]);
                ph[g][1] = fmaf(gvk, w1, ph[g][1]);
                ph[g][2] = fmaf(gvk, w2, ph[g][2]);
                ph[g][3] = fmaf(gvk, w3, ph[g][3]);
            }
        }
    }
    #pragma unroll
    for (int g = 0; g < 4; g++)
        #pragma unroll
        for (int mm = 0; mm < 4; mm++)
            red_l[wave][g][c4 + 64 * mm] = ph[g][mm];
    __syncthreads();

    {
        const int g = wave;
        float part = 0.f;
        #pragma unroll
        for (int mm = 0; mm < 4; mm++) {
            const int c = c4 + 64 * mm;
            float sum = mlp1_b[c] + red_l[0][g][c] + red_l[1][g][c]
                      + red_l[2][g][c] + red_l[3][g][c];
            float s = mlp1_g[c] * rsqrtf(1.f + EPS_BN);
            float val = fmaxf(fmaf(sum, s, mlp1_bb[c]), 0.f);
            part = fmaf(val, mlp2_w[c], part);
        }
        #pragma unroll
        for (int off = 32; off > 0; off >>= 1) part += __shfl_xor(part, off, 64);
        if (lane == 0) {
            const int gg = blk * 4 + g;
            float mm = mask_t[gg * GPER];
            #pragma unroll
            for (int n = 1; n < GPER; n++) mm = fmaxf(mm, mask_t[gg * GPER + n]);
            out[gg] = (mm == 1.0f) ? (part + mlp2_b[0]) : 0.f;
        }
    }
}

// ---------------------------------------------------------------------------
extern "C" void kernel_launch(void* const* d_in, const int* in_sizes, int n_in,
                              void* d_out, int out_size, void* d_ws, size_t ws_size,
                              hipStream_t stream)
{
    const float* x        = (const float*)d_in[0];
    const float* pos      = (const float*)d_in[1];
    const float* normal   = (const float*)d_in[2];
    const float* mask_t   = (const float*)d_in[3];
    const int*   src      = (const int*)d_in[5];
    const float* lin_w    = (const float*)d_in[7];
    const float* lin_b    = (const float*)d_in[8];
    const float* src_w    = (const float*)d_in[9];
    const float* dst_w    = (const float*)d_in[10];
    const float* posnn_w  = (const float*)d_in[11];
    const float* posnn_b  = (const float*)d_in[12];
    const float* posnn_g  = (const float*)d_in[13];
    const float* posnn_bb = (const float*)d_in[14];
    const float* attnn_w  = (const float*)d_in[15];
    const float* attnn_b  = (const float*)d_in[16];
    const float* attnn_g  = (const float*)d_in[17];
    const float* attnn_bb = (const float*)d_in[18];
    const float* neck_w   = (const float*)d_in[19];
    const float* neck_b   = (const float*)d_in[20];
    const float* neck_g   = (const float*)d_in[21];
    const float* neck_bb  = (const float*)d_in[22];
    const float* mlp1_w   = (const float*)d_in[23];
    const float* mlp1_b   = (const float*)d_in[24];
    const float* mlp1_g   = (const float*)d_in[25];
    const float* mlp1_bb  = (const float*)d_in[26];
    const float* mlp2_w   = (const float*)d_in[27];
    const float* mlp2_b   = (const float*)d_in[28];

    float* ws = (float*)d_ws;
    float2*   vx   = (float2*)ws;                              // N*H float2
    float*    xdb  = (float*)(vx + (size_t)N_NODES * H);       // N*H
    unsigned* h2   = (unsigned*)(xdb + (size_t)N_NODES * H);   // N*H
    short*    w3hi = (short*)(h2 + (size_t)N_NODES * H);       // 24576
    short*    w3lo = w3hi + 24576;
    short*    pwhi = w3lo + 24576;                             // 2048
    short*    pwlo = pwhi + 2048;
    short*    awhi = pwlo + 2048;                              // 16384
    short*    awlo = awhi + H * H;
    short*    nwhi = awlo + H * H;                             // 65536
    short*    nwlo = nwhi + H * NECK;

    prep_kernel<<<F_INPUT + 2 + 64 + 256, 256, 0, stream>>>(
        lin_w, src_w, dst_w, posnn_w, attnn_w, attnn_g, neck_w,
        w3hi, w3lo, pwhi, pwlo, awhi, awlo, nwhi, nwlo);
    proj_kernel<<<N_NODES / 32, 256, 0, stream>>>(x, lin_b, attnn_g, attnn_b, attnn_bb,
                                                  w3hi, w3lo, vx, xdb);
    edge_kernel<<<N_NODES / 2, 256, 0, stream>>>(pos, normal, src, vx, xdb,
                                                 posnn_b, posnn_g, posnn_bb,
                                                 pwhi, pwlo, awhi, awlo, h2);
    neck_head_kernel<<<N_NODES / 32, 256, 0, stream>>>(
        h2, nwhi, nwlo, neck_b, neck_g, neck_bb, mask_t,
        mlp1_w, mlp1_b, mlp1_g, mlp1_bb, mlp2_w, mlp2_b, (float*)d_out);
}

// Round 9
// 202.792 us; speedup vs baseline: 1.2286x; 1.2286x over previous
//
#include <hip/hip_runtime.h>
#include <hip/hip_bf16.h>
#include <cmath>

#define N_NODES 8192
#define F_INPUT 59
#define H 128
#define K 32
#define NECK 512
#define GPER 8
#define NG 1024
#define EPS_BN 1e-5f
#define DPITCH 136   // bf16 row pitch for neck staging (272 B)
#define XPITCH 72    // proj x-plane pitch (144 B)
#define PLANE 272    // padded plane stride (shorts) for edge A-frag planes (544 B)

typedef short bf16x8 __attribute__((ext_vector_type(8)));
typedef float f32x16 __attribute__((ext_vector_type(16)));

// truncation hi/lo split
__device__ __forceinline__ void split_bf(float v, short& hi, short& lo) {
    unsigned u = __float_as_uint(v);
    float hif = __uint_as_float(u & 0xffff0000u);
    hi = (short)(u >> 16);
    lo = (short)(__float_as_uint(v - hif) >> 16);
}
// round-to-nearest bf16
__device__ __forceinline__ short f2bfrn(float f) {
    __hip_bfloat16 b = __float2bfloat16(f);
    return *reinterpret_cast<short*>(&b);
}

// B-frag flat index for 32x32x16: c = ct*32+ln, k = s*16+hf*8+kk
__device__ __forceinline__ int bfrag_idx(int k, int c, int k16) {
    int ct = c >> 5, ln = c & 31;
    int s = k >> 4, hf = (k >> 3) & 1, kk = k & 7;
    return ((((ct * k16 + s) * 2 + hf) * 32 + ln) * 8 + kk);
}

// ---------------------------------------------------------------------------
// Prep (fused):
//   [0,59)   : row f of W3 = [lin_w | src_w@attnn_w | dst_w@attnn_w] -> pack
//   59       : zero-pad W3 rows k=59..63
//   60       : pack posnn_w -> B-frag (K16=1, K padded 6->16)
//   [61,125) : pack attnn_w, columns pre-scaled by attnn BN scale (K16=8)
//   [125,381): pack neck_w (K16=8)
// ---------------------------------------------------------------------------
__global__ __launch_bounds__(256) void prep_kernel(
    const float* __restrict__ lin_w,
    const float* __restrict__ src_w, const float* __restrict__ dst_w,
    const float* __restrict__ posnn_w,
    const float* __restrict__ attnn_w, const float* __restrict__ attnn_g,
    const float* __restrict__ neck_w,
    short* __restrict__ w3hi, short* __restrict__ w3lo,
    short* __restrict__ pwhi, short* __restrict__ pwlo,
    short* __restrict__ awhi, short* __restrict__ awlo,
    short* __restrict__ nwhi, short* __restrict__ nwlo)
{
    const int b = blockIdx.x;
    if (b < F_INPUT) {
        const int c = threadIdx.x;
        if (c < H) {
            float a1 = 0.f, a2 = 0.f;
            for (int k = 0; k < H; k++) {
                float wa = attnn_w[k * H + c];
                a1 = fmaf(src_w[b * H + k], wa, a1);
                a2 = fmaf(dst_w[b * H + k], wa, a2);
            }
            short hi, lo; int idx;
            split_bf(lin_w[b * H + c], hi, lo);
            idx = bfrag_idx(b, c, 4);       w3hi[idx] = hi; w3lo[idx] = lo;
            split_bf(a1, hi, lo);
            idx = bfrag_idx(b, 128 + c, 4); w3hi[idx] = hi; w3lo[idx] = lo;
            split_bf(a2, hi, lo);
            idx = bfrag_idx(b, 256 + c, 4); w3hi[idx] = hi; w3lo[idx] = lo;
        }
    } else if (b == F_INPUT) {
        for (int t = threadIdx.x; t < 5 * 384; t += 256) {
            int k = F_INPUT + t / 384, c = t % 384;
            int idx = bfrag_idx(k, c, 4);
            w3hi[idx] = 0; w3lo[idx] = 0;
        }
    } else if (b == F_INPUT + 1) {
        // posnn pack: 2048 entries, K16=1
        for (int idx = threadIdx.x; idx < 2048; idx += 256) {
            int kk = idx & 7; int t = idx >> 3;
            int l2 = t & 31; t >>= 5;
            int hb = t & 1;  t >>= 1;
            int ct = t;
            int k = hb * 8 + kk, c = ct * 32 + l2;
            float wv = (k < 6) ? posnn_w[k * H + c] : 0.f;
            short hi, lo; split_bf(wv, hi, lo);
            pwhi[idx] = hi; pwlo[idx] = lo;
        }
    } else if (b < F_INPUT + 2 + 64) {
        int idx = (b - F_INPUT - 2) * 256 + threadIdx.x;
        int kk = idx & 7; int t = idx >> 3;
        int l2 = t & 31; t >>= 5;
        int hb = t & 1;  t >>= 1;
        int s  = t & 7;  t >>= 3;
        int c = t * 32 + l2, k = s * 16 + hb * 8 + kk;
        float scale = attnn_g[c] * rsqrtf(1.f + EPS_BN);
        short hi, lo; split_bf(attnn_w[k * H + c] * scale, hi, lo);
        awhi[idx] = hi; awlo[idx] = lo;
    } else {
        int idx = (b - F_INPUT - 2 - 64) * 256 + threadIdx.x;
        int kk = idx & 7; int t = idx >> 3;
        int l2 = t & 31; t >>= 5;
        int hb = t & 1;  t >>= 1;
        int s  = t & 7;  t >>= 3;
        int c = t * 32 + l2, k = s * 16 + hb * 8 + kk;
        short hi, lo; split_bf(neck_w[k * NECK + c], hi, lo);
        nwhi[idx] = hi; nwlo[idx] = lo;
    }
}

// ---------------------------------------------------------------------------
// Kernel A: proj via MFMA. Block = 32 nodes, 4 waves. attnn BN scale folded:
//   vx[node][c] = (as_*xs, v);  xdb[node][c] = as_*xd + (as_*attnn_b + attnn_bb)
// ---------------------------------------------------------------------------
__global__ __launch_bounds__(256) void proj_kernel(
    const float* __restrict__ x, const float* __restrict__ lin_b,
    const float* __restrict__ attnn_g, const float* __restrict__ attnn_b,
    const float* __restrict__ attnn_bb,
    const short* __restrict__ w3hi, const short* __restrict__ w3lo,
    float2* __restrict__ vx, float* __restrict__ xdb)
{
    const int n0 = blockIdx.x * 32;
    const int tid = threadIdx.x;
    const int wave = tid >> 6;
    const int lane = tid & 63;
    const int hf = lane >> 5;
    const int ln = lane & 31;

    __shared__ __align__(16) short xhi[32][XPITCH];
    __shared__ __align__(16) short xlo[32][XPITCH];

    for (int idx = tid; idx < 32 * F_INPUT; idx += 256) {
        int n = idx / F_INPUT, k = idx - n * F_INPUT;
        short hi, lo; split_bf(x[n0 * F_INPUT + idx], hi, lo);
        xhi[n][k] = hi; xlo[n][k] = lo;
    }
    if (tid < 32 * 5) {
        int n = tid / 5, k = F_INPUT + tid % 5;
        xhi[n][k] = 0; xlo[n][k] = 0;
    }
    __syncthreads();

    f32x16 acc[3];
    #pragma unroll
    for (int t = 0; t < 3; t++)
        #pragma unroll
        for (int r = 0; r < 16; r++) acc[t][r] = 0.f;

    #pragma unroll
    for (int s = 0; s < 4; s++) {
        bf16x8 ah = *(const bf16x8*)&xhi[ln][s * 16 + hf * 8];
        bf16x8 al = *(const bf16x8*)&xlo[ln][s * 16 + hf * 8];
        #pragma unroll
        for (int t = 0; t < 3; t++) {
            const int ct = wave + 4 * t;
            const int boff = (((ct * 4 + s) * 2 + hf) * 32 + ln) * 8;
            bf16x8 bh = *(const bf16x8*)&w3hi[boff];
            bf16x8 bl = *(const bf16x8*)&w3lo[boff];
            acc[t] = __builtin_amdgcn_mfma_f32_32x32x16_bf16(ah, bl, acc[t], 0, 0, 0);
            acc[t] = __builtin_amdgcn_mfma_f32_32x32x16_bf16(al, bh, acc[t], 0, 0, 0);
            acc[t] = __builtin_amdgcn_mfma_f32_32x32x16_bf16(ah, bh, acc[t], 0, 0, 0);
        }
    }
    const int c = wave * 32 + ln;
    const float lb  = lin_b[c];
    const float as_ = attnn_g[c] * rsqrtf(1.f + EPS_BN);
    const float cbn = fmaf(attnn_b[c], as_, attnn_bb[c]);
    #pragma unroll
    for (int r = 0; r < 16; r++) {
        int node = n0 + (r & 3) + 8 * (r >> 2) + 4 * hf;
        vx[node * H + c] = make_float2(as_ * acc[1][r], acc[0][r] + lb);
        xdb[node * H + c] = fmaf(acc[2][r], as_, cbn);
    }
}

// ---------------------------------------------------------------------------
// Kernel B: edge, 2 nodes/block (grid 4096). Lane-contiguous A-frag planes.
// Delta kept in fp32 REGISTERS (n-loop fully unrolled -> constant indexing;
// R8's unroll(disable) demoted dreg to scratch = 134 MB HBM spill traffic).
// ---------------------------------------------------------------------------
__global__ __launch_bounds__(256) void edge_kernel(
    const float* __restrict__ pos, const float* __restrict__ normal,
    const int* __restrict__ src,
    const float2* __restrict__ vx, const float* __restrict__ xdb,
    const float* __restrict__ posnn_b, const float* __restrict__ posnn_g,
    const float* __restrict__ posnn_bb,
    const short* __restrict__ pwhi, const short* __restrict__ pwlo,
    const short* __restrict__ awhi, const short* __restrict__ awlo,
    unsigned* __restrict__ h2)
{
    const int i0 = blockIdx.x * 2;
    const int tid = threadIdx.x;
    const int wave = tid >> 6;
    const int lane = tid & 63;
    const int hf = lane >> 5;
    const int ln = lane & 31;

    __shared__ int srcs[2][K];
    __shared__ __align__(16) short relh[4 * PLANE];   // planes [n*2+hf]
    __shared__ __align__(16) short rell[4 * PLANE];
    __shared__ __align__(16) short dpk[32 * PLANE];   // planes [(n*8+s)*2+hf]

    if (tid < 64) {
        int n = tid >> 5, jj = tid & 31;
        int i = i0 + n;
        int s = src[i * K + jj];
        srcs[n][jj] = s;
        short h_, l_;
        const int b0 = (n * 2) * PLANE + jj * 8;       // hf=0 plane
        const int b1 = (n * 2 + 1) * PLANE + jj * 8;   // hf=1 plane
        #pragma unroll
        for (int k = 0; k < 3; k++) {
            split_bf(pos[i * 3 + k] - pos[s * 3 + k], h_, l_);
            relh[b0 + k] = h_; rell[b0 + k] = l_;
            split_bf(normal[i * 3 + k] - normal[s * 3 + k], h_, l_);
            relh[b0 + k + 3] = h_; rell[b0 + k + 3] = l_;
        }
        #pragma unroll
        for (int k = 6; k < 8; k++) { relh[b0 + k] = 0; rell[b0 + k] = 0; }
        #pragma unroll
        for (int k = 0; k < 8; k++) { relh[b1 + k] = 0; rell[b1 + k] = 0; }
    }

    const int cc = wave * 32 + ln;
    const float ps  = posnn_g[cc] * rsqrtf(1.f + EPS_BN);
    const float pbn = fmaf(posnn_b[cc], ps, posnn_bb[cc]);

    // posnn B-frag (K16=1, ct=wave)
    const bf16x8 pbh = *(const bf16x8*)&pwhi[((wave * 2 + hf) * 32 + ln) * 8];
    const bf16x8 pbl = *(const bf16x8*)&pwlo[((wave * 2 + hf) * 32 + ln) * 8];

    // delta write position for this lane (row j varies per r)
    const int dbase = ((cc >> 4) * 2 + ((cc >> 3) & 1)) * PLANE + (cc & 7);

    __syncthreads();

    // ---- delta via MFMA, kept in regs + bf16(RN) to LDS planes
    float dreg[2][16];
    #pragma unroll
    for (int n = 0; n < 2; n++) {
        bf16x8 ah = *(const bf16x8*)&relh[(n * 2 + hf) * PLANE + ln * 8];
        bf16x8 al = *(const bf16x8*)&rell[(n * 2 + hf) * PLANE + ln * 8];
        f32x16 da;
        #pragma unroll
        for (int r = 0; r < 16; r++) da[r] = 0.f;
        da = __builtin_amdgcn_mfma_f32_32x32x16_bf16(ah, pbl, da, 0, 0, 0);
        da = __builtin_amdgcn_mfma_f32_32x32x16_bf16(al, pbh, da, 0, 0, 0);
        da = __builtin_amdgcn_mfma_f32_32x32x16_bf16(ah, pbh, da, 0, 0, 0);
        #pragma unroll
        for (int r = 0; r < 16; r++) {
            int j = (r & 3) + 8 * (r >> 2) + 4 * hf;
            float d = fmaxf(fmaf(da[r], ps, pbn), 0.f);
            dreg[n][r] = d;
            dpk[n * 16 * PLANE + dbase + j * 8] = f2bfrn(d);
        }
    }
    __syncthreads();

    // ---- attnn MFMA (weights pre-scaled) + softmax epilogue per node
    const short* whb = awhi + wave * 8 * 2 * 32 * 8;
    const short* wlb = awlo + wave * 8 * 2 * 32 * 8;

    #pragma unroll
    for (int n = 0; n < 2; n++) {
        const int i = i0 + n;
        f32x16 acc;
        #pragma unroll
        for (int r = 0; r < 16; r++) acc[r] = 0.f;
        #pragma unroll
        for (int s = 0; s < 8; s++) {
            bf16x8 ah = *(const bf16x8*)&dpk[((n * 8 + s) * 2 + hf) * PLANE + ln * 8];
            const int boff = ((s * 2 + hf) * 32 + ln) * 8;
            bf16x8 bh = *(const bf16x8*)&whb[boff];
            bf16x8 bl = *(const bf16x8*)&wlb[boff];
            acc = __builtin_amdgcn_mfma_f32_32x32x16_bf16(ah, bh, acc, 0, 0, 0);
            acc = __builtin_amdgcn_mfma_f32_32x32x16_bf16(ah, bl, acc, 0, 0, 0);
        }

        const float base = xdb[i * H + cc];
        float a[16], vv[16];
        float m = 0.f;   // relu floor
        #pragma unroll
        for (int r = 0; r < 16; r++) {
            int j = (r & 3) + 8 * (r >> 2) + 4 * hf;
            float2 g = vx[srcs[n][j] * H + cc];
            float av = fmaxf(acc[r] + base - g.x, 0.f);
            a[r] = av; vv[r] = g.y;
            m = fmaxf(m, av);
        }
        m = fmaxf(m, __shfl_xor(m, 32, 64));
        float den = 0.f;
        #pragma unroll
        for (int r = 0; r < 16; r++) {
            float e = __expf(a[r] - m);
            a[r] = e; den += e;
        }
        den += __shfl_xor(den, 32, 64);
        const float inv = 1.f / (den + 1e-16f);

        float hsum = 0.f;
        #pragma unroll
        for (int r = 0; r < 16; r++)
            hsum = fmaf(a[r], vv[r] + dreg[n][r], hsum);
        hsum += __shfl_xor(hsum, 32, 64);
        hsum *= inv;
        if (hf == 0) {
            unsigned u = __float_as_uint(hsum);
            unsigned hib = u & 0xffff0000u;
            unsigned lo = __float_as_uint(hsum - __uint_as_float(hib)) >> 16;
            h2[i * H + cc] = (lo << 16) | (u >> 16);
        }
    }
}

// ---------------------------------------------------------------------------
// Kernel C (fused): neck MFMA + bn_relu + residue max-pool + head.
// ---------------------------------------------------------------------------
__global__ __launch_bounds__(256) void neck_head_kernel(
    const unsigned* __restrict__ h2,
    const short* __restrict__ nwhi, const short* __restrict__ nwlo,
    const float* __restrict__ neck_b, const float* __restrict__ neck_g,
    const float* __restrict__ neck_bb,
    const float* __restrict__ mask_t,
    const float* __restrict__ mlp1_w, const float* __restrict__ mlp1_b,
    const float* __restrict__ mlp1_g, const float* __restrict__ mlp1_bb,
    const float* __restrict__ mlp2_w, const float* __restrict__ mlp2_b,
    float* __restrict__ out)
{
    const int blk = blockIdx.x;
    const int n0 = blk * 32;
    const int tid = threadIdx.x;
    const int wave = tid >> 6;
    const int lane = tid & 63;
    const int hf = lane >> 5;
    const int ln = lane & 31;

    __shared__ __align__(16) short a_hi[32][DPITCH];
    __shared__ __align__(16) short a_lo[32][DPITCH];
    __shared__ float gfeat_l[4][NECK];
    __shared__ float red_l[4][4][256];

    for (int d = tid; d < 32 * H; d += 256) {
        unsigned u = h2[(n0 + (d >> 7)) * H + (d & 127)];
        a_hi[d >> 7][d & 127] = (short)(u & 0xffffu);
        a_lo[d >> 7][d & 127] = (short)(u >> 16);
    }
    __syncthreads();

    f32x16 acc[4];
    #pragma unroll
    for (int t = 0; t < 4; t++)
        #pragma unroll
        for (int r = 0; r < 16; r++) acc[t][r] = 0.f;

    #pragma unroll
    for (int s = 0; s < 8; s++) {
        bf16x8 ah = *(const bf16x8*)&a_hi[ln][s * 16 + hf * 8];
        bf16x8 al = *(const bf16x8*)&a_lo[ln][s * 16 + hf * 8];
        #pragma unroll
        for (int t = 0; t < 4; t++) {
            const int ct = wave * 4 + t;
            const int boff = (((ct * 8 + s) * 2 + hf) * 32 + ln) * 8;
            bf16x8 bh = *(const bf16x8*)&nwhi[boff];
            bf16x8 bl = *(const bf16x8*)&nwlo[boff];
            acc[t] = __builtin_amdgcn_mfma_f32_32x32x16_bf16(ah, bl, acc[t], 0, 0, 0);
            acc[t] = __builtin_amdgcn_mfma_f32_32x32x16_bf16(al, bh, acc[t], 0, 0, 0);
            acc[t] = __builtin_amdgcn_mfma_f32_32x32x16_bf16(ah, bh, acc[t], 0, 0, 0);
        }
    }

    #pragma unroll
    for (int t = 0; t < 4; t++) {
        const int c = wave * 128 + t * 32 + ln;
        const float s  = neck_g[c] * rsqrtf(1.f + EPS_BN);
        const float bnb = fmaf(neck_b[c], s, neck_bb[c]);
        #pragma unroll
        for (int g = 0; g < 4; g++) {
            float m = 0.f;
            #pragma unroll
            for (int q = 0; q < 4; q++)
                m = fmaxf(m, fmaf(acc[t][4 * g + q], s, bnb));
            m = fmaxf(m, __shfl_xor(m, 32, 64));
            if (hf == 0) gfeat_l[g][c] = m;
        }
    }
    __syncthreads();

    const int c4 = lane;
    float ph[4][4];
    #pragma unroll
    for (int g = 0; g < 4; g++)
        #pragma unroll
        for (int mm = 0; mm < 4; mm++) ph[g][mm] = 0.f;

    const int k0 = wave * 128;
    for (int k = 0; k < 128; k += 4) {
        float4 gv[4];
        #pragma unroll
        for (int g = 0; g < 4; g++) gv[g] = *(const float4*)&gfeat_l[g][k0 + k];
        #pragma unroll
        for (int kk = 0; kk < 4; kk++) {
            float w0 = mlp1_w[(k0 + k + kk) * 256 + c4];
            float w1 = mlp1_w[(k0 + k + kk) * 256 + c4 + 64];
            float w2 = mlp1_w[(k0 + k + kk) * 256 + c4 + 128];
            float w3 = mlp1_w[(k0 + k + kk) * 256 + c4 + 192];
            #pragma unroll
            for (int g = 0; g < 4; g++) {
                float gvk = (&gv[g].x)[kk];
                ph[g][0] = fmaf(gvk, w0, ph[g][0]);
                ph[g][1] = fmaf(gvk, w1, ph[g][1]);
                ph[g][2] = fmaf(gvk, w2, ph[g][2]);
                ph[g][3] = fmaf(gvk, w3, ph[g][3]);
            }
        }
    }
    #pragma unroll
    for (int g = 0; g < 4; g++)
        #pragma unroll
        for (int mm = 0; mm < 4; mm++)
            red_l[wave][g][c4 + 64 * mm] = ph[g][mm];
    __syncthreads();

    {
        const int g = wave;
        float part = 0.f;
        #pragma unroll
        for (int mm = 0; mm < 4; mm++) {
            const int c = c4 + 64 * mm;
            float sum = mlp1_b[c] + red_l[0][g][c] + red_l[1][g][c]
                      + red_l[2][g][c] + red_l[3][g][c];
            float s = mlp1_g[c] * rsqrtf(1.f + EPS_BN);
            float val = fmaxf(fmaf(sum, s, mlp1_bb[c]), 0.f);
            part = fmaf(val, mlp2_w[c], part);
        }
        #pragma unroll
        for (int off = 32; off > 0; off >>= 1) part += __shfl_xor(part, off, 64);
        if (lane == 0) {
            const int gg = blk * 4 + g;
            float mm = mask_t[gg * GPER];
            #pragma unroll
            for (int n = 1; n < GPER; n++) mm = fmaxf(mm, mask_t[gg * GPER + n]);
            out[gg] = (mm == 1.0f) ? (part + mlp2_b[0]) : 0.f;
        }
    }
}

// ---------------------------------------------------------------------------
extern "C" void kernel_launch(void* const* d_in, const int* in_sizes, int n_in,
                              void* d_out, int out_size, void* d_ws, size_t ws_size,
                              hipStream_t stream)
{
    const float* x        = (const float*)d_in[0];
    const float* pos      = (const float*)d_in[1];
    const float* normal   = (const float*)d_in[2];
    const float* mask_t   = (const float*)d_in[3];
    const int*   src      = (const int*)d_in[5];
    const float* lin_w    = (const float*)d_in[7];
    const float* lin_b    = (const float*)d_in[8];
    const float* src_w    = (const float*)d_in[9];
    const float* dst_w    = (const float*)d_in[10];
    const float* posnn_w  = (const float*)d_in[11];
    const float* posnn_b  = (const float*)d_in[12];
    const float* posnn_g  = (const float*)d_in[13];
    const float* posnn_bb = (const float*)d_in[14];
    const float* attnn_w  = (const float*)d_in[15];
    const float* attnn_b  = (const float*)d_in[16];
    const float* attnn_g  = (const float*)d_in[17];
    const float* attnn_bb = (const float*)d_in[18];
    const float* neck_w   = (const float*)d_in[19];
    const float* neck_b   = (const float*)d_in[20];
    const float* neck_g   = (const float*)d_in[21];
    const float* neck_bb  = (const float*)d_in[22];
    const float* mlp1_w   = (const float*)d_in[23];
    const float* mlp1_b   = (const float*)d_in[24];
    const float* mlp1_g   = (const float*)d_in[25];
    const float* mlp1_bb  = (const float*)d_in[26];
    const float* mlp2_w   = (const float*)d_in[27];
    const float* mlp2_b   = (const float*)d_in[28];

    float* ws = (float*)d_ws;
    float2*   vx   = (float2*)ws;                              // N*H float2
    float*    xdb  = (float*)(vx + (size_t)N_NODES * H);       // N*H
    unsigned* h2   = (unsigned*)(xdb + (size_t)N_NODES * H);   // N*H
    short*    w3hi = (short*)(h2 + (size_t)N_NODES * H);       // 24576
    short*    w3lo = w3hi + 24576;
    short*    pwhi = w3lo + 24576;                             // 2048
    short*    pwlo = pwhi + 2048;
    short*    awhi = pwlo + 2048;                              // 16384
    short*    awlo = awhi + H * H;
    short*    nwhi = awlo + H * H;                             // 65536
    short*    nwlo = nwhi + H * NECK;

    prep_kernel<<<F_INPUT + 2 + 64 + 256, 256, 0, stream>>>(
        lin_w, src_w, dst_w, posnn_w, attnn_w, attnn_g, neck_w,
        w3hi, w3lo, pwhi, pwlo, awhi, awlo, nwhi, nwlo);
    proj_kernel<<<N_NODES / 32, 256, 0, stream>>>(x, lin_b, attnn_g, attnn_b, attnn_bb,
                                                  w3hi, w3lo, vx, xdb);
    edge_kernel<<<N_NODES / 2, 256, 0, stream>>>(pos, normal, src, vx, xdb,
                                                 posnn_b, posnn_g, posnn_bb,
                                                 pwhi, pwlo, awhi, awlo, h2);
    neck_head_kernel<<<N_NODES / 32, 256, 0, stream>>>(
        h2, nwhi, nwlo, neck_b, neck_g, neck_bb, mask_t,
        mlp1_w, mlp1_b, mlp1_g, mlp1_bb, mlp2_w, mlp2_b, (float*)d_out);
}